// Round 3
// baseline (638.553 us; speedup 1.0000x reference)
//
#include <hip/hip_runtime.h>
#include <hip/hip_bf16.h>

#define R_RES 384
#define S_SEQ 128
#define CM 256
#define CC 32
#define CZ 128

typedef __attribute__((ext_vector_type(8))) short bf16x8;
typedef __attribute__((ext_vector_type(4))) float f32x4;
typedef __attribute__((ext_vector_type(4))) int i32x4;

__device__ __forceinline__ short tobf16(float f) {
    union { __hip_bfloat16 h; short s; } u;
    u.h = __float2bfloat16(f);
    return u.s;
}

// ---------------- kernel 0a: w_out (1024,128) f32 -> wbT (128,1024) bf16 ----------------
__global__ void k_transpose_wout(const float* __restrict__ w_out, short* __restrict__ wbT) {
    __shared__ float t[64][65];
    int k0 = blockIdx.x * 64;   // 16 blocks over k=1024
    int z0 = blockIdx.y * 64;   // 2 blocks over z=128
    int tid = threadIdx.x;
    int c = tid & 63, rg = tid >> 6;
#pragma unroll
    for (int rr = 0; rr < 16; ++rr) {
        int kk = rg * 16 + rr;
        t[kk][c] = w_out[(size_t)(k0 + kk) * CZ + z0 + c];
    }
    __syncthreads();
#pragma unroll
    for (int rr = 0; rr < 16; ++rr) {
        int zz = rg * 16 + rr;
        wbT[(size_t)(z0 + zz) * 1024 + k0 + c] = tobf16(t[c][zz]);
    }
}

// ---------------- kernel 0b: pack w1|w2 (256,32) -> wcT (64,256) bf16 ----------------
__global__ void k_pack_w12(const float* __restrict__ w1, const float* __restrict__ w2,
                           short* __restrict__ wcT) {
    int idx = blockIdx.x * 256 + threadIdx.x;   // 64 blocks -> 16384
    int k = idx >> 6, n = idx & 63;
    float v = (n < 32) ? w1[k * CC + n] : w2[k * CC + (n - 32)];
    wcT[n * CM + k] = tobf16(v);
}

// ---------------- kernel 1: LayerNorm + projections -> aT[m][s], bT[n][s] bf16 ----------------
__global__ __launch_bounds__(256) void k_ln_proj(
    const float* __restrict__ M, const float* __restrict__ ln_g, const float* __restrict__ ln_b,
    const float* __restrict__ b1, const float* __restrict__ b2,
    const short* __restrict__ wcT, short* __restrict__ aT, short* __restrict__ bT) {
    __shared__ short mnb[64 * 256];      // [s_loc][k] bf16, XOR-swizzled, 32 KB
    __shared__ short ab_s[2][32 * 72];   // [x][s_loc] stride-72 transpose buffers
    int r = blockIdx.x >> 1;
    int s0 = (blockIdx.x & 1) * 64;
    int tid = threadIdx.x, lane = tid & 63, w = tid >> 6;
    int g = lane >> 4, r16 = lane & 15;
    float4 gv = *(const float4*)(ln_g + lane * 4);
    float4 bv = *(const float4*)(ln_b + lane * 4);
    for (int it = 0; it < 16; ++it) {
        int sl = it * 4 + w;   // 0..63
        float4 v = *(const float4*)(M + ((size_t)(s0 + sl) * R_RES + r) * CM + lane * 4);
        float sum = v.x + v.y + v.z + v.w;
        float sq = v.x * v.x + v.y * v.y + v.z * v.z + v.w * v.w;
#pragma unroll
        for (int off = 32; off; off >>= 1) {
            sum += __shfl_xor(sum, off);
            sq  += __shfl_xor(sq, off);
        }
        float mu = sum * (1.0f / 256.0f);
        float var = sq * (1.0f / 256.0f) - mu * mu;
        float rstd = rsqrtf(var + 1e-5f);
        short4 mnp;
        mnp.x = tobf16((v.x - mu) * rstd * gv.x + bv.x);
        mnp.y = tobf16((v.y - mu) * rstd * gv.y + bv.y);
        mnp.z = tobf16((v.z - mu) * rstd * gv.z + bv.z);
        mnp.w = tobf16((v.w - mu) * rstd * gv.w + bv.w);
        int byte = sl * 512 + lane * 8;
        byte ^= ((sl & 7) << 4);
        *(short4*)((char*)mnb + byte) = mnp;
    }
    __syncthreads();
    f32x4 acc[4] = {{0,0,0,0},{0,0,0,0},{0,0,0,0},{0,0,0,0}};
    int srow = w * 16 + r16;
#pragma unroll
    for (int ks = 0; ks < 8; ++ks) {
        int byte = srow * 512 + ks * 64 + g * 16;
        byte ^= ((srow & 7) << 4);
        bf16x8 af = *(const bf16x8*)((const char*)mnb + byte);
#pragma unroll
        for (int nt = 0; nt < 4; ++nt) {
            bf16x8 bf = *(const bf16x8*)(wcT + (nt * 16 + r16) * CM + ks * 32 + g * 8);
            acc[nt] = __builtin_amdgcn_mfma_f32_16x16x32_bf16(af, bf, acc[nt], 0, 0, 0);
        }
    }
#pragma unroll
    for (int nt = 0; nt < 4; ++nt) {
        int n = nt * 16 + r16;
        int x = n & 31, sel = n >> 5;
        float bias = sel ? b2[x] : b1[x];
#pragma unroll
        for (int rr = 0; rr < 4; ++rr) {
            int sl = w * 16 + g * 4 + rr;
            ab_s[sel][x * 72 + sl] = tobf16(acc[nt][rr] + bias);
        }
    }
    __syncthreads();
    int o = tid * 16;           // bytes over 4 KB chunk
    int x = o >> 7, sb = o & 127;
    i32x4 va = *(const i32x4*)((const char*)ab_s[0] + x * 144 + sb);
    i32x4 vb = *(const i32x4*)((const char*)ab_s[1] + x * 144 + sb);
    *(i32x4*)((char*)aT + (size_t)(r * 32 + x) * 256 + s0 * 2 + sb) = va;
    *(i32x4*)((char*)bT + (size_t)(r * 32 + x) * 256 + s0 * 2 + sb) = vb;
}

// ---------------- kernel 2: persistent fused outer-product + w_out contraction ----------------
// grid = 768 blocks x 512 thr (8 waves). Block b: bi = b>>3 (fixed A-strip, 4 res),
// iterates 12 bj tiles. wbT held in registers (32 x bf16x8 per thread). LDS = 32KB A2 only.
__global__ __launch_bounds__(512, 6) void k_opm(
    const short* __restrict__ aT, const short* __restrict__ bT,
    const short* __restrict__ wbT, const float* __restrict__ b_out,
    float* __restrict__ out) {
    __shared__ __align__(16) char A2[32768];   // [16 p][1024 k] bf16, dual-XOR swizzled
    int tid = threadIdx.x, lane = tid & 63, w = tid >> 6;
    int g = lane >> 4, r16 = lane & 15;
    int wm = w >> 1, wn = w & 1;               // ph2 wave split: m 4x32, n 2x64
    int b = blockIdx.x;
    int bi = b >> 3;
    int bj0 = (b & 7) * 12;
    int z = w * 16 + r16;

    // preload wbT fragments for this thread's z (static indexing -> stays in VGPRs)
    bf16x8 wb[32];
#pragma unroll
    for (int ks2 = 0; ks2 < 32; ++ks2)
        wb[ks2] = *(const bf16x8*)(wbT + (size_t)z * 1024 + ks2 * 32 + g * 8);
    float bo = b_out[z];

    const char* gA = (const char*)(aT + (size_t)bi * 128 * 128);

    for (int it = 0; it < 12; ++it) {
        int bj = bj0 + it;
        const char* gB = (const char*)(bT + (size_t)bj * 128 * 128);

        // ---- ph2: O[128x128] = sum_s a*b, operands direct from L2.
        // mfma(bfr, af): lane holds O[m = wm*32+mi*16+r16][n = wn*64+ni*16+g*4+rr]
        f32x4 acc[2][4] = {};
#pragma unroll
        for (int ks = 0; ks < 4; ++ks) {
            bf16x8 bfr[4];
#pragma unroll
            for (int ni = 0; ni < 4; ++ni) {
                int n = wn * 64 + ni * 16 + r16;
                bfr[ni] = *(const bf16x8*)(gB + n * 256 + ks * 64 + g * 16);
            }
#pragma unroll
            for (int mi = 0; mi < 2; ++mi) {
                int m = wm * 32 + mi * 16 + r16;
                bf16x8 af = *(const bf16x8*)(gA + m * 256 + ks * 64 + g * 16);
#pragma unroll
                for (int ni = 0; ni < 4; ++ni)
                    acc[mi][ni] = __builtin_amdgcn_mfma_f32_16x16x32_bf16(bfr[ni], af, acc[mi][ni], 0, 0, 0);
            }
        }
        __syncthreads();   // previous tile's ph4 reads of A2 complete

        // ---- ph3: reorg O -> A2 bf16 [p = i*4+j][k = x*32+y], dual-XOR swizzle
#pragma unroll
        for (int mi = 0; mi < 2; ++mi)
#pragma unroll
            for (int ni = 0; ni < 4; ++ni) {
                int p = wm * 4 + wn * 2 + (ni >> 1);
                int x = mi * 16 + r16;
                int y0 = (ni & 1) * 16 + g * 4;
                int byte = p * 2048 + x * 64 + y0 * 2;
                byte ^= (((p & 7) ^ (x & 7)) << 4);
                short4 pk;
                pk.x = tobf16(acc[mi][ni][0]);
                pk.y = tobf16(acc[mi][ni][1]);
                pk.z = tobf16(acc[mi][ni][2]);
                pk.w = tobf16(acc[mi][ni][3]);
                *(short4*)(A2 + byte) = pk;
            }
        __syncthreads();

        // ---- ph4: out[16 p][128 z] = A2(16x1024) x wbT^T from regs; 4 indep acc chains
        f32x4 c0 = {0,0,0,0}, c1 = {0,0,0,0}, c2 = {0,0,0,0}, c3 = {0,0,0,0};
        int abase = r16 * 2048 + g * 16;
        int rsw = (r16 & 7) << 4;
#pragma unroll
        for (int kq = 0; kq < 8; ++kq) {
            bf16x8 a0 = *(const bf16x8*)(A2 + ((abase + (kq * 4 + 0) * 64) ^ (rsw ^ ((((kq * 4 + 0) & 7)) << 4))));
            bf16x8 a1 = *(const bf16x8*)(A2 + ((abase + (kq * 4 + 1) * 64) ^ (rsw ^ ((((kq * 4 + 1) & 7)) << 4))));
            bf16x8 a2 = *(const bf16x8*)(A2 + ((abase + (kq * 4 + 2) * 64) ^ (rsw ^ ((((kq * 4 + 2) & 7)) << 4))));
            bf16x8 a3 = *(const bf16x8*)(A2 + ((abase + (kq * 4 + 3) * 64) ^ (rsw ^ ((((kq * 4 + 3) & 7)) << 4))));
            c0 = __builtin_amdgcn_mfma_f32_16x16x32_bf16(a0, wb[kq * 4 + 0], c0, 0, 0, 0);
            c1 = __builtin_amdgcn_mfma_f32_16x16x32_bf16(a1, wb[kq * 4 + 1], c1, 0, 0, 0);
            c2 = __builtin_amdgcn_mfma_f32_16x16x32_bf16(a2, wb[kq * 4 + 2], c2, 0, 0, 0);
            c3 = __builtin_amdgcn_mfma_f32_16x16x32_bf16(a3, wb[kq * 4 + 3], c3, 0, 0, 0);
        }
        f32x4 ct;
#pragma unroll
        for (int rr = 0; rr < 4; ++rr) ct[rr] = (c0[rr] + c1[rr]) + (c2[rr] + c3[rr]);

        // ---- epilogue: (acc + b_out) / S ; p = g*4+rr, ig = bi*4 + p>>2, jg = bj*4 + p&3
#pragma unroll
        for (int rr = 0; rr < 4; ++rr) {
            int p = g * 4 + rr;
            int ig = bi * 4 + (p >> 2);
            int jg = bj * 4 + (p & 3);
            out[((size_t)ig * R_RES + jg) * CZ + z] = (ct[rr] + bo) * (1.0f / 128.0f);
        }
    }
}

extern "C" void kernel_launch(void* const* d_in, const int* in_sizes, int n_in,
                              void* d_out, int out_size, void* d_ws, size_t ws_size,
                              hipStream_t stream) {
    const float* M     = (const float*)d_in[0];
    const float* ln_g  = (const float*)d_in[1];
    const float* ln_b  = (const float*)d_in[2];
    const float* w1    = (const float*)d_in[3];
    const float* b1    = (const float*)d_in[4];
    const float* w2    = (const float*)d_in[5];
    const float* b2    = (const float*)d_in[6];
    const float* w_out = (const float*)d_in[7];
    const float* b_out = (const float*)d_in[8];
    float* out = (float*)d_out;

    short* aT  = (short*)d_ws;              // 12288 x 128 bf16
    short* bT  = aT + 12288 * 128;          // 12288 x 128 bf16
    short* wbT = bT + 12288 * 128;          // 128 x 1024 bf16
    short* wcT = wbT + 128 * 1024;          // 64 x 256 bf16

    k_transpose_wout<<<dim3(16, 2), 256, 0, stream>>>(w_out, wbT);
    k_pack_w12<<<64, 256, 0, stream>>>(w1, w2, wcT);
    k_ln_proj<<<768, 256, 0, stream>>>(M, ln_g, ln_b, b1, b2, wcT, aT, bT);
    k_opm<<<768, 512, 0, stream>>>(aT, bT, wbT, b_out, out);
}

// Round 4
// 296.344 us; speedup vs baseline: 2.1548x; 2.1548x over previous
//
#include <hip/hip_runtime.h>
#include <hip/hip_bf16.h>

#define R_RES 384
#define S_SEQ 128
#define CM 256
#define CC 32
#define CZ 128

typedef __attribute__((ext_vector_type(8))) short bf16x8;
typedef __attribute__((ext_vector_type(4))) float f32x4;
typedef __attribute__((ext_vector_type(4))) int i32x4;

__device__ __forceinline__ short tobf16(float f) {
    union { __hip_bfloat16 h; short s; } u;
    u.h = __float2bfloat16(f);
    return u.s;
}

// ---------------- kernel 0a: w_out (1024,128) f32 -> wbT (128,1024) bf16 ----------------
__global__ void k_transpose_wout(const float* __restrict__ w_out, short* __restrict__ wbT) {
    __shared__ float t[64][65];
    int k0 = blockIdx.x * 64;
    int z0 = blockIdx.y * 64;
    int tid = threadIdx.x;
    int c = tid & 63, rg = tid >> 6;
#pragma unroll
    for (int rr = 0; rr < 16; ++rr) {
        int kk = rg * 16 + rr;
        t[kk][c] = w_out[(size_t)(k0 + kk) * CZ + z0 + c];
    }
    __syncthreads();
#pragma unroll
    for (int rr = 0; rr < 16; ++rr) {
        int zz = rg * 16 + rr;
        wbT[(size_t)(z0 + zz) * 1024 + k0 + c] = tobf16(t[c][zz]);
    }
}

// ---------------- kernel 0b: pack w1|w2 (256,32) -> wcT (64,256) bf16 ----------------
__global__ void k_pack_w12(const float* __restrict__ w1, const float* __restrict__ w2,
                           short* __restrict__ wcT) {
    int idx = blockIdx.x * 256 + threadIdx.x;
    int k = idx >> 6, n = idx & 63;
    float v = (n < 32) ? w1[k * CC + n] : w2[k * CC + (n - 32)];
    wcT[n * CM + k] = tobf16(v);
}

// ---------------- kernel 1: LayerNorm + projections -> aT[m][s], bT[n][s] bf16 ----------------
__global__ __launch_bounds__(256) void k_ln_proj(
    const float* __restrict__ M, const float* __restrict__ ln_g, const float* __restrict__ ln_b,
    const float* __restrict__ b1, const float* __restrict__ b2,
    const short* __restrict__ wcT, short* __restrict__ aT, short* __restrict__ bT) {
    __shared__ short mnb[64 * 256];
    __shared__ short ab_s[2][32 * 72];
    int r = blockIdx.x >> 1;
    int s0 = (blockIdx.x & 1) * 64;
    int tid = threadIdx.x, lane = tid & 63, w = tid >> 6;
    int g = lane >> 4, r16 = lane & 15;
    float4 gv = *(const float4*)(ln_g + lane * 4);
    float4 bv = *(const float4*)(ln_b + lane * 4);
    for (int it = 0; it < 16; ++it) {
        int sl = it * 4 + w;
        float4 v = *(const float4*)(M + ((size_t)(s0 + sl) * R_RES + r) * CM + lane * 4);
        float sum = v.x + v.y + v.z + v.w;
        float sq = v.x * v.x + v.y * v.y + v.z * v.z + v.w * v.w;
#pragma unroll
        for (int off = 32; off; off >>= 1) {
            sum += __shfl_xor(sum, off);
            sq  += __shfl_xor(sq, off);
        }
        float mu = sum * (1.0f / 256.0f);
        float var = sq * (1.0f / 256.0f) - mu * mu;
        float rstd = rsqrtf(var + 1e-5f);
        short4 mnp;
        mnp.x = tobf16((v.x - mu) * rstd * gv.x + bv.x);
        mnp.y = tobf16((v.y - mu) * rstd * gv.y + bv.y);
        mnp.z = tobf16((v.z - mu) * rstd * gv.z + bv.z);
        mnp.w = tobf16((v.w - mu) * rstd * gv.w + bv.w);
        int byte = sl * 512 + lane * 8;
        byte ^= ((sl & 7) << 4);
        *(short4*)((char*)mnb + byte) = mnp;
    }
    __syncthreads();
    f32x4 acc[4] = {{0,0,0,0},{0,0,0,0},{0,0,0,0},{0,0,0,0}};
    int srow = w * 16 + r16;
#pragma unroll
    for (int ks = 0; ks < 8; ++ks) {
        int byte = srow * 512 + ks * 64 + g * 16;
        byte ^= ((srow & 7) << 4);
        bf16x8 af = *(const bf16x8*)((const char*)mnb + byte);
#pragma unroll
        for (int nt = 0; nt < 4; ++nt) {
            bf16x8 bf = *(const bf16x8*)(wcT + (nt * 16 + r16) * CM + ks * 32 + g * 8);
            acc[nt] = __builtin_amdgcn_mfma_f32_16x16x32_bf16(af, bf, acc[nt], 0, 0, 0);
        }
    }
#pragma unroll
    for (int nt = 0; nt < 4; ++nt) {
        int n = nt * 16 + r16;
        int x = n & 31, sel = n >> 5;
        float bias = sel ? b2[x] : b1[x];
#pragma unroll
        for (int rr = 0; rr < 4; ++rr) {
            int sl = w * 16 + g * 4 + rr;
            ab_s[sel][x * 72 + sl] = tobf16(acc[nt][rr] + bias);
        }
    }
    __syncthreads();
    int o = tid * 16;
    int x = o >> 7, sb = o & 127;
    i32x4 va = *(const i32x4*)((const char*)ab_s[0] + x * 144 + sb);
    i32x4 vb = *(const i32x4*)((const char*)ab_s[1] + x * 144 + sb);
    *(i32x4*)((char*)aT + (size_t)(r * 32 + x) * 256 + s0 * 2 + sb) = va;
    *(i32x4*)((char*)bT + (size_t)(r * 32 + x) * 256 + s0 * 2 + sb) = vb;
}

// ---------------- kernel 2: persistent fused outer-product + w_out contraction ----------------
// 256 blocks x 512 thr (8 waves), 36 tiles/block of 128x128 O each.
// wbT in registers (wb[2][16], 128 VGPR). LDS: B-strip 32K + A2 32K + partials 16K = 80K.
// 3 barriers/tile. ph4 split: k-half (w&1) x z-quarter (w>>1), f32 partials + coalesced reduce.
__global__ __launch_bounds__(512, 2) void k_opm(
    const short* __restrict__ aT, const short* __restrict__ bT,
    const short* __restrict__ wbT, const float* __restrict__ b_out,
    float* __restrict__ out) {
    __shared__ __align__(16) char Bb[32768];
    __shared__ __align__(16) char A2[32768];
    __shared__ __align__(16) char Pp[16384];
    int tid = threadIdx.x, lane = tid & 63, w = tid >> 6;
    int g = lane >> 4, r16 = lane & 15;
    int wr = w & 1, wc = w >> 1;     // ph2 roles: row-half, col-quarter
    int kh = w & 1, zq = w >> 1;     // ph4 roles: k-half, z-quarter

    // persistent wbT fragments: z = zq*32 + n3*16 + r16, k = kh*512 + ks2*32 + g*8
    bf16x8 wb[2][16];
#pragma unroll
    for (int n3 = 0; n3 < 2; ++n3)
#pragma unroll
        for (int ks2 = 0; ks2 < 16; ++ks2)
            wb[n3][ks2] = *(const bf16x8*)(wbT + (size_t)(zq * 32 + n3 * 16 + r16) * 1024
                                           + kh * 512 + ks2 * 32 + g * 8);

    int pr = tid >> 5;               // reduce role: p row
    int z0 = (tid & 31) * 4;         // reduce role: z quad
    float4 bo4 = *(const float4*)(b_out + z0);
    bo4.x *= 0.0078125f; bo4.y *= 0.0078125f; bo4.z *= 0.0078125f; bo4.w *= 0.0078125f;
    int keyr = ((pr >> 2) & 3) << 5;

    int tidx = blockIdx.x * 36;
    const char* Abase = (const char*)aT;
    const char* Bbase = (const char*)bT;

    // prologue: stage B(0), prefetch A(0)
    {
        const char* gB = Bbase + (size_t)(tidx % 96) * 32768;
#pragma unroll
        for (int kk = 0; kk < 4; ++kk) {
            int q = kk * 8192 + tid * 16;
            int src = q ^ (((q >> 8) & 7) << 4);
            __builtin_amdgcn_global_load_lds(
                (const __attribute__((address_space(1))) void*)(gB + src),
                (__attribute__((address_space(3))) void*)(Bb + q), 16, 0, 0);
        }
    }
    bf16x8 af[4][4];
    {
        const char* gA = Abase + (size_t)(tidx / 96) * 32768;
#pragma unroll
        for (int mi = 0; mi < 4; ++mi)
#pragma unroll
            for (int ks = 0; ks < 4; ++ks)
                af[mi][ks] = *(const bf16x8*)(gA + (wr * 64 + mi * 16 + r16) * 256 + ks * 64 + g * 16);
    }
    __syncthreads();

    for (int it = 0; it < 36; ++it, ++tidx) {
        // ---- ph2: O[128x128] += A-rows (regs) x B (LDS). 32 MFMA/wave.
        f32x4 acc[4][2] = {};
#pragma unroll
        for (int ks = 0; ks < 4; ++ks) {
            int n0 = wc * 32 + r16;
            int n1 = n0 + 16;
            bf16x8 b0 = *(const bf16x8*)(Bb + ((n0 * 256 + ks * 64 + g * 16) ^ ((n0 & 7) << 4)));
            bf16x8 b1 = *(const bf16x8*)(Bb + ((n1 * 256 + ks * 64 + g * 16) ^ ((n1 & 7) << 4)));
#pragma unroll
            for (int mi = 0; mi < 4; ++mi) {
                acc[mi][0] = __builtin_amdgcn_mfma_f32_16x16x32_bf16(b0, af[mi][ks], acc[mi][0], 0, 0, 0);
                acc[mi][1] = __builtin_amdgcn_mfma_f32_16x16x32_bf16(b1, af[mi][ks], acc[mi][1], 0, 0, 0);
            }
        }
        __syncthreads();   // b1: B reads + prev A2/Pp reads done

        if (it < 35) {     // stage B(t+1) into Bb (async; drains at b2)
            const char* gB = Bbase + (size_t)((tidx + 1) % 96) * 32768;
#pragma unroll
            for (int kk = 0; kk < 4; ++kk) {
                int q = kk * 8192 + tid * 16;
                int src = q ^ (((q >> 8) & 7) << 4);
                __builtin_amdgcn_global_load_lds(
                    (const __attribute__((address_space(1))) void*)(gB + src),
                    (__attribute__((address_space(3))) void*)(Bb + q), 16, 0, 0);
            }
        }

        // ---- ph3: O -> A2 bf16 [p=i*4+j][k=x*32+y], dual-XOR swizzle
#pragma unroll
        for (int mi = 0; mi < 4; ++mi)
#pragma unroll
            for (int ni = 0; ni < 2; ++ni) {
                int p = (wr * 2 + (mi >> 1)) * 4 + wc;
                int x = (mi & 1) * 16 + r16;
                int y0 = ni * 16 + g * 4;
                int byte = (p * 2048 + x * 64 + y0 * 2) ^ (((p & 7) ^ (x & 7)) << 4);
                short4 pk;
                pk.x = tobf16(acc[mi][ni][0]);
                pk.y = tobf16(acc[mi][ni][1]);
                pk.z = tobf16(acc[mi][ni][2]);
                pk.w = tobf16(acc[mi][ni][3]);
                *(short4*)(A2 + byte) = pk;
            }
        __syncthreads();   // b2: A2 visible; B-stage drained

        if (it < 35) {     // prefetch A(t+1) into regs (drains at b3, covered by ph4)
            const char* gA = Abase + (size_t)((tidx + 1) / 96) * 32768;
#pragma unroll
            for (int mi = 0; mi < 4; ++mi)
#pragma unroll
                for (int ks = 0; ks < 4; ++ks)
                    af[mi][ks] = *(const bf16x8*)(gA + (wr * 64 + mi * 16 + r16) * 256 + ks * 64 + g * 16);
        }

        // ---- ph4: partial[p][z] over k-half; wave = (kh, zq). 32 MFMA/wave.
        f32x4 c0 = {0,0,0,0}, c1 = {0,0,0,0};
#pragma unroll
        for (int ks2 = 0; ks2 < 16; ++ks2) {
            int kc = kh * 16 + ks2;
            int byte = (r16 * 2048 + kc * 64 + g * 16) ^ ((((r16 & 7) ^ (kc & 7))) << 4);
            bf16x8 a2f = *(const bf16x8*)(A2 + byte);
            c0 = __builtin_amdgcn_mfma_f32_16x16x32_bf16(a2f, wb[0][ks2], c0, 0, 0, 0);
            c1 = __builtin_amdgcn_mfma_f32_16x16x32_bf16(a2f, wb[1][ks2], c1, 0, 0, 0);
        }
        // partial store: Pp[kh][p][z] f32, XOR (p>>2)<<5 for bank spread
#pragma unroll
        for (int rr = 0; rr < 4; ++rr) {
            int p4 = g * 4 + rr;
            int za = zq * 32 + r16;
            int ba0 = (((kh * 16 + p4) * 128 + za) * 4) ^ (g << 5);
            int ba1 = (((kh * 16 + p4) * 128 + za + 16) * 4) ^ (g << 5);
            *(float*)(Pp + ba0) = c0[rr];
            *(float*)(Pp + ba1) = c1[rr];
        }
        __syncthreads();   // b3: partials visible; A-prefetch drained

        // ---- reduce + coalesced f32x4 store
        {
            float4 v0 = *(const float4*)(Pp + (((pr * 128 + z0) * 4) ^ keyr));
            float4 v1 = *(const float4*)(Pp + ((((16 + pr) * 128 + z0) * 4) ^ keyr));
            float4 res;
            res.x = (v0.x + v1.x) * 0.0078125f + bo4.x;
            res.y = (v0.y + v1.y) * 0.0078125f + bo4.y;
            res.z = (v0.z + v1.z) * 0.0078125f + bo4.z;
            res.w = (v0.w + v1.w) * 0.0078125f + bo4.w;
            int ig = (tidx / 96) * 4 + (pr >> 2);
            int jg = (tidx % 96) * 4 + (pr & 3);
            *(float4*)(out + ((size_t)ig * R_RES + jg) * CZ + z0) = res;
        }
    }
}

extern "C" void kernel_launch(void* const* d_in, const int* in_sizes, int n_in,
                              void* d_out, int out_size, void* d_ws, size_t ws_size,
                              hipStream_t stream) {
    const float* M     = (const float*)d_in[0];
    const float* ln_g  = (const float*)d_in[1];
    const float* ln_b  = (const float*)d_in[2];
    const float* w1    = (const float*)d_in[3];
    const float* b1    = (const float*)d_in[4];
    const float* w2    = (const float*)d_in[5];
    const float* b2    = (const float*)d_in[6];
    const float* w_out = (const float*)d_in[7];
    const float* b_out = (const float*)d_in[8];
    float* out = (float*)d_out;

    short* aT  = (short*)d_ws;              // 12288 x 128 bf16
    short* bT  = aT + 12288 * 128;          // 12288 x 128 bf16
    short* wbT = bT + 12288 * 128;          // 128 x 1024 bf16
    short* wcT = wbT + 128 * 1024;          // 64 x 256 bf16

    k_transpose_wout<<<dim3(16, 2), 256, 0, stream>>>(w_out, wbT);
    k_pack_w12<<<64, 256, 0, stream>>>(w1, w2, wcT);
    k_ln_proj<<<768, 256, 0, stream>>>(M, ln_g, ln_b, b1, b2, wcT, aT, bT);
    k_opm<<<256, 512, 0, stream>>>(aT, bT, wbT, b_out, out);
}

// Round 5
// 232.193 us; speedup vs baseline: 2.7501x; 1.2763x over previous
//
#include <hip/hip_runtime.h>
#include <hip/hip_bf16.h>

#define R_RES 384
#define S_SEQ 128
#define CM 256
#define CC 32
#define CZ 128

typedef __attribute__((ext_vector_type(8))) short bf16x8;
typedef __attribute__((ext_vector_type(4))) float f32x4;
typedef __attribute__((ext_vector_type(4))) int i32x4;

__device__ __forceinline__ short tobf16(float f) {
    union { __hip_bfloat16 h; short s; } u;
    u.h = __float2bfloat16(f);
    return u.s;
}

// ---------------- kernel 0a: w_out (1024,128) f32 -> wbT (128,1024) bf16 ----------------
__global__ void k_transpose_wout(const float* __restrict__ w_out, short* __restrict__ wbT) {
    __shared__ float t[64][65];
    int k0 = blockIdx.x * 64;
    int z0 = blockIdx.y * 64;
    int tid = threadIdx.x;
    int c = tid & 63, rg = tid >> 6;
#pragma unroll
    for (int rr = 0; rr < 16; ++rr) {
        int kk = rg * 16 + rr;
        t[kk][c] = w_out[(size_t)(k0 + kk) * CZ + z0 + c];
    }
    __syncthreads();
#pragma unroll
    for (int rr = 0; rr < 16; ++rr) {
        int zz = rg * 16 + rr;
        wbT[(size_t)(z0 + zz) * 1024 + k0 + c] = tobf16(t[c][zz]);
    }
}

// ---------------- kernel 0b: pack w1|w2 (256,32) -> wcT (64,256) bf16 ----------------
__global__ void k_pack_w12(const float* __restrict__ w1, const float* __restrict__ w2,
                           short* __restrict__ wcT) {
    int idx = blockIdx.x * 256 + threadIdx.x;
    int k = idx >> 6, n = idx & 63;
    float v = (n < 32) ? w1[k * CC + n] : w2[k * CC + (n - 32)];
    wcT[n * CM + k] = tobf16(v);
}

// ---------------- kernel 1: LayerNorm + projections -> aT[m][s], bT[n][s] bf16 ----------------
__global__ __launch_bounds__(256) void k_ln_proj(
    const float* __restrict__ M, const float* __restrict__ ln_g, const float* __restrict__ ln_b,
    const float* __restrict__ b1, const float* __restrict__ b2,
    const short* __restrict__ wcT, short* __restrict__ aT, short* __restrict__ bT) {
    __shared__ short mnb[64 * 256];
    __shared__ short ab_s[2][32 * 72];
    int r = blockIdx.x >> 1;
    int s0 = (blockIdx.x & 1) * 64;
    int tid = threadIdx.x, lane = tid & 63, w = tid >> 6;
    int g = lane >> 4, r16 = lane & 15;
    float4 gv = *(const float4*)(ln_g + lane * 4);
    float4 bv = *(const float4*)(ln_b + lane * 4);
    for (int it = 0; it < 16; ++it) {
        int sl = it * 4 + w;
        float4 v = *(const float4*)(M + ((size_t)(s0 + sl) * R_RES + r) * CM + lane * 4);
        float sum = v.x + v.y + v.z + v.w;
        float sq = v.x * v.x + v.y * v.y + v.z * v.z + v.w * v.w;
#pragma unroll
        for (int off = 32; off; off >>= 1) {
            sum += __shfl_xor(sum, off);
            sq  += __shfl_xor(sq, off);
        }
        float mu = sum * (1.0f / 256.0f);
        float var = sq * (1.0f / 256.0f) - mu * mu;
        float rstd = rsqrtf(var + 1e-5f);
        short4 mnp;
        mnp.x = tobf16((v.x - mu) * rstd * gv.x + bv.x);
        mnp.y = tobf16((v.y - mu) * rstd * gv.y + bv.y);
        mnp.z = tobf16((v.z - mu) * rstd * gv.z + bv.z);
        mnp.w = tobf16((v.w - mu) * rstd * gv.w + bv.w);
        int byte = sl * 512 + lane * 8;
        byte ^= ((sl & 7) << 4);
        *(short4*)((char*)mnb + byte) = mnp;
    }
    __syncthreads();
    f32x4 acc[4] = {{0,0,0,0},{0,0,0,0},{0,0,0,0},{0,0,0,0}};
    int srow = w * 16 + r16;
#pragma unroll
    for (int ks = 0; ks < 8; ++ks) {
        int byte = srow * 512 + ks * 64 + g * 16;
        byte ^= ((srow & 7) << 4);
        bf16x8 af = *(const bf16x8*)((const char*)mnb + byte);
#pragma unroll
        for (int nt = 0; nt < 4; ++nt) {
            bf16x8 bf = *(const bf16x8*)(wcT + (nt * 16 + r16) * CM + ks * 32 + g * 8);
            acc[nt] = __builtin_amdgcn_mfma_f32_16x16x32_bf16(af, bf, acc[nt], 0, 0, 0);
        }
    }
#pragma unroll
    for (int nt = 0; nt < 4; ++nt) {
        int n = nt * 16 + r16;
        int x = n & 31, sel = n >> 5;
        float bias = sel ? b2[x] : b1[x];
#pragma unroll
        for (int rr = 0; rr < 4; ++rr) {
            int sl = w * 16 + g * 4 + rr;
            ab_s[sel][x * 72 + sl] = tobf16(acc[nt][rr] + bias);
        }
    }
    __syncthreads();
    int o = tid * 16;
    int x = o >> 7, sb = o & 127;
    i32x4 va = *(const i32x4*)((const char*)ab_s[0] + x * 144 + sb);
    i32x4 vb = *(const i32x4*)((const char*)ab_s[1] + x * 144 + sb);
    *(i32x4*)((char*)aT + (size_t)(r * 32 + x) * 256 + s0 * 2 + sb) = va;
    *(i32x4*)((char*)bT + (size_t)(r * 32 + x) * 256 + s0 * 2 + sb) = vb;
}

// ---------------- kernel 2: fused outer-product + w_out contraction ----------------
// grid (96 bj, 48 bi), 512 thr (8 waves), O-tile 256(i:8res) x 128(j:4res).
// LDS 64 KB total: [0,32K) = B-strip during ph2, whole [0,64K) = A2 (32p x 1024k bf16) after.
// 2 blocks/CU (VGPR<=128, LDS 64K). 3 barriers. A-frags from L2, wbT from L2 (1x/block).
__global__ __launch_bounds__(512, 4) void k_opm(
    const short* __restrict__ aT, const short* __restrict__ bT,
    const short* __restrict__ wbT, const float* __restrict__ b_out,
    float* __restrict__ out) {
    __shared__ __align__(16) char smem[65536];
    int tid = threadIdx.x, lane = tid & 63, w = tid >> 6;
    int g = lane >> 4, r16 = lane & 15;
    int wm = w & 3, wn = w >> 2;            // ph2 wave grid: 4(m-64) x 2(n-64)
    int bj = blockIdx.x, bi = blockIdx.y;
    const char* gA = (const char*)(aT + (size_t)bi * 256 * 128);
    const char* gB = (const char*)(bT + (size_t)bj * 128 * 128);

    // ---- stage B-strip (32 KB) into smem[0,32K): linear dest, pre-swizzled source
#pragma unroll
    for (int it = 0; it < 4; ++it) {
        int q = it * 8192 + tid * 16;
        int src = q ^ (((q >> 8) & 7) << 4);
        __builtin_amdgcn_global_load_lds(
            (const __attribute__((address_space(1))) void*)(gB + src),
            (__attribute__((address_space(3))) void*)(smem + q), 16, 0, 0);
    }
    int z = w * 16 + r16;                   // ph4 role (wz = w)
    float bo = b_out[z];
    __syncthreads();

    // ---- ph2: O[256x128] = sum_s a b. acc[mi][ni]: m=wm*64+mi*16+r16, n=wn*64+ni*16+g*4+rr
    f32x4 acc[4][4] = {};
#pragma unroll
    for (int ks = 0; ks < 4; ++ks) {
        bf16x8 bf[4], af[4];
#pragma unroll
        for (int ni = 0; ni < 4; ++ni) {
            int n = wn * 64 + ni * 16 + r16;
            bf[ni] = *(const bf16x8*)(smem + ((n * 256 + ks * 64 + g * 16) ^ ((n & 7) << 4)));
        }
#pragma unroll
        for (int mi = 0; mi < 4; ++mi) {
            int m = wm * 64 + mi * 16 + r16;
            af[mi] = *(const bf16x8*)(gA + m * 256 + ks * 64 + g * 16);
        }
        __builtin_amdgcn_s_setprio(1);
#pragma unroll
        for (int mi = 0; mi < 4; ++mi)
#pragma unroll
            for (int ni = 0; ni < 4; ++ni)
                acc[mi][ni] = __builtin_amdgcn_mfma_f32_16x16x32_bf16(bf[ni], af[mi], acc[mi][ni], 0, 0, 0);
        __builtin_amdgcn_s_setprio(0);
    }
    __syncthreads();   // B-strip reads done -> smem becomes A2

    // ---- ph3: O -> A2 bf16 [p = i*4+j][k = x*32+y], dual-XOR swizzle
#pragma unroll
    for (int mi = 0; mi < 4; ++mi)
#pragma unroll
        for (int ni = 0; ni < 4; ++ni) {
            int m = wm * 64 + mi * 16 + r16;
            int nb = wn * 64 + ni * 16 + g * 4;
            int i = m >> 5, x = m & 31;
            int j = nb >> 5, y0 = nb & 31;
            int p = i * 4 + j;
            int byte = (p * 2048 + x * 64 + y0 * 2) ^ (((p & 7) ^ (x & 7)) << 4);
            short4 pk;
            pk.x = tobf16(acc[mi][ni][0]);
            pk.y = tobf16(acc[mi][ni][1]);
            pk.z = tobf16(acc[mi][ni][2]);
            pk.w = tobf16(acc[mi][ni][3]);
            *(short4*)(smem + byte) = pk;
        }
    __syncthreads();

    // ---- ph4: out[32p][128z] = A2(32x1024) x wbT^T(1024x128); wave w -> z-frag w
    f32x4 c0 = {0,0,0,0}, c1 = {0,0,0,0};
#pragma unroll 8
    for (int ks2 = 0; ks2 < 32; ++ks2) {
        bf16x8 wbf = *(const bf16x8*)(wbT + (size_t)z * 1024 + ks2 * 32 + g * 8);
        int key = ((r16 & 7) ^ (ks2 & 7)) << 4;
        bf16x8 a0 = *(const bf16x8*)(smem + ((r16 * 2048 + ks2 * 64 + g * 16) ^ key));
        bf16x8 a1 = *(const bf16x8*)(smem + (((16 + r16) * 2048 + ks2 * 64 + g * 16) ^ key));
        __builtin_amdgcn_s_setprio(1);
        c0 = __builtin_amdgcn_mfma_f32_16x16x32_bf16(a0, wbf, c0, 0, 0, 0);
        c1 = __builtin_amdgcn_mfma_f32_16x16x32_bf16(a1, wbf, c1, 0, 0, 0);
        __builtin_amdgcn_s_setprio(0);
    }

    // ---- epilogue: (acc + b_out) / S; p = pf*16 + g*4 + rr
#pragma unroll
    for (int rr = 0; rr < 4; ++rr) {
        int p0 = g * 4 + rr;
        int p1 = 16 + p0;
        out[((size_t)(bi * 8 + (p0 >> 2)) * R_RES + bj * 4 + (p0 & 3)) * CZ + z] =
            (c0[rr] + bo) * (1.0f / 128.0f);
        out[((size_t)(bi * 8 + (p1 >> 2)) * R_RES + bj * 4 + (p1 & 3)) * CZ + z] =
            (c1[rr] + bo) * (1.0f / 128.0f);
    }
}

extern "C" void kernel_launch(void* const* d_in, const int* in_sizes, int n_in,
                              void* d_out, int out_size, void* d_ws, size_t ws_size,
                              hipStream_t stream) {
    const float* M     = (const float*)d_in[0];
    const float* ln_g  = (const float*)d_in[1];
    const float* ln_b  = (const float*)d_in[2];
    const float* w1    = (const float*)d_in[3];
    const float* b1    = (const float*)d_in[4];
    const float* w2    = (const float*)d_in[5];
    const float* b2    = (const float*)d_in[6];
    const float* w_out = (const float*)d_in[7];
    const float* b_out = (const float*)d_in[8];
    float* out = (float*)d_out;

    short* aT  = (short*)d_ws;              // 12288 x 128 bf16
    short* bT  = aT + 12288 * 128;          // 12288 x 128 bf16
    short* wbT = bT + 12288 * 128;          // 128 x 1024 bf16
    short* wcT = wbT + 128 * 1024;          // 64 x 256 bf16

    k_transpose_wout<<<dim3(16, 2), 256, 0, stream>>>(w_out, wbT);
    k_pack_w12<<<64, 256, 0, stream>>>(w1, w2, wcT);
    k_ln_proj<<<768, 256, 0, stream>>>(M, ln_g, ln_b, b1, b2, wcT, aT, bT);
    k_opm<<<dim3(96, 48), 512, 0, stream>>>(aT, bT, wbT, b_out, out);
}

// Round 6
// 133.804 us; speedup vs baseline: 4.7723x; 1.7353x over previous
//
#include <hip/hip_runtime.h>
#include <hip/hip_bf16.h>

#define R_RES 384
#define S_SEQ 128
#define CM 256
#define CC 32
#define CZ 128

typedef __attribute__((ext_vector_type(8))) short bf16x8;
typedef __attribute__((ext_vector_type(4))) float f32x4;
typedef __attribute__((ext_vector_type(16))) float f32x16;
typedef __attribute__((ext_vector_type(4))) int i32x4;

__device__ __forceinline__ short tobf16(float f) {
    union { __hip_bfloat16 h; short s; } u;
    u.h = __float2bfloat16(f);
    return u.s;
}

// ---------------- kernel 0a: w_out (1024,128) f32 -> wbTf fragment-tiled bf16 ----------------
// wbTf[(fz*64 + ks16)*64 + lane][8]: z = fz*32 + (lane&31), k = ks16*16 + (lane>>5)*8 + j
__global__ void k_transpose_wout(const float* __restrict__ w_out, short* __restrict__ wbTf) {
    __shared__ float t[64][65];
    int k0 = blockIdx.x * 64;   // 16 blocks over k=1024
    int z0 = blockIdx.y * 64;   // 2 blocks over z=128
    int tid = threadIdx.x;
    int c = tid & 63, rg = tid >> 6;
#pragma unroll
    for (int rr = 0; rr < 16; ++rr) {
        int kk = rg * 16 + rr;
        t[kk][c] = w_out[(size_t)(k0 + kk) * CZ + z0 + c];
    }
    __syncthreads();
#pragma unroll
    for (int l = 0; l < 2; ++l) {
        int id = l * 256 + tid;
        int f = id >> 6;               // 0..7
        int ksl = f >> 1, fzl = f & 1;
        int ln = id & 63;
        int zl = fzl * 32 + (ln & 31);
        int kl = ksl * 16 + (ln >> 5) * 8;
        bf16x8 pk;
#pragma unroll
        for (int j = 0; j < 8; ++j) pk[j] = tobf16(t[kl + j][zl]);
        size_t fz = blockIdx.y * 2 + fzl;
        size_t ks16 = blockIdx.x * 4 + ksl;
        *(bf16x8*)(wbTf + ((fz * 64 + ks16) * 64 + ln) * 8) = pk;
    }
}

// ---------------- kernel 0b: pack w1|w2 (256,32) -> wcT (64,256) bf16 ----------------
__global__ void k_pack_w12(const float* __restrict__ w1, const float* __restrict__ w2,
                           short* __restrict__ wcT) {
    int idx = blockIdx.x * 256 + threadIdx.x;
    int k = idx >> 6, n = idx & 63;
    float v = (n < 32) ? w1[k * CC + n] : w2[k * CC + (n - 32)];
    wcT[n * CM + k] = tobf16(v);
}

// ---------------- kernel 1: LayerNorm + projections -> aTf, bTf fragment-tiled bf16 ----------------
// aTf frag(fm16, ks32)[lane][8]: m = fm16*16 + (lane&15), s = ks32*32 + (lane>>4)*8 + j
__global__ __launch_bounds__(256) void k_ln_proj(
    const float* __restrict__ M, const float* __restrict__ ln_g, const float* __restrict__ ln_b,
    const float* __restrict__ b1, const float* __restrict__ b2,
    const short* __restrict__ wcT, short* __restrict__ aTf, short* __restrict__ bTf) {
    __shared__ short mnb[64 * 256];      // [s_loc][k] bf16, XOR-swizzled, 32 KB
    __shared__ short ab_s[2][32 * 72];   // [x][s_loc] stride-72 transpose buffers
    int r = blockIdx.x >> 1;
    int s0 = (blockIdx.x & 1) * 64;
    int tid = threadIdx.x, lane = tid & 63, w = tid >> 6;
    int g = lane >> 4, r16 = lane & 15;
    float4 gv = *(const float4*)(ln_g + lane * 4);
    float4 bv = *(const float4*)(ln_b + lane * 4);
    for (int it = 0; it < 16; ++it) {
        int sl = it * 4 + w;
        float4 v = *(const float4*)(M + ((size_t)(s0 + sl) * R_RES + r) * CM + lane * 4);
        float sum = v.x + v.y + v.z + v.w;
        float sq = v.x * v.x + v.y * v.y + v.z * v.z + v.w * v.w;
#pragma unroll
        for (int off = 32; off; off >>= 1) {
            sum += __shfl_xor(sum, off);
            sq  += __shfl_xor(sq, off);
        }
        float mu = sum * (1.0f / 256.0f);
        float var = sq * (1.0f / 256.0f) - mu * mu;
        float rstd = rsqrtf(var + 1e-5f);
        short4 mnp;
        mnp.x = tobf16((v.x - mu) * rstd * gv.x + bv.x);
        mnp.y = tobf16((v.y - mu) * rstd * gv.y + bv.y);
        mnp.z = tobf16((v.z - mu) * rstd * gv.z + bv.z);
        mnp.w = tobf16((v.w - mu) * rstd * gv.w + bv.w);
        int byte = sl * 512 + lane * 8;
        byte ^= ((sl & 7) << 4);
        *(short4*)((char*)mnb + byte) = mnp;
    }
    __syncthreads();
    f32x4 acc[4] = {{0,0,0,0},{0,0,0,0},{0,0,0,0},{0,0,0,0}};
    int srow = w * 16 + r16;
#pragma unroll
    for (int ks = 0; ks < 8; ++ks) {
        int byte = srow * 512 + ks * 64 + g * 16;
        byte ^= ((srow & 7) << 4);
        bf16x8 af = *(const bf16x8*)((const char*)mnb + byte);
#pragma unroll
        for (int nt = 0; nt < 4; ++nt) {
            bf16x8 bf = *(const bf16x8*)(wcT + (nt * 16 + r16) * CM + ks * 32 + g * 8);
            acc[nt] = __builtin_amdgcn_mfma_f32_16x16x32_bf16(af, bf, acc[nt], 0, 0, 0);
        }
    }
#pragma unroll
    for (int nt = 0; nt < 4; ++nt) {
        int n = nt * 16 + r16;
        int x = n & 31, sel = n >> 5;
        float bias = sel ? b2[x] : b1[x];
#pragma unroll
        for (int rr = 0; rr < 4; ++rr) {
            int sl = w * 16 + g * 4 + rr;
            ab_s[sel][x * 72 + sl] = tobf16(acc[nt][rr] + bias);
        }
    }
    __syncthreads();
    // fragment-tiled write-out: fm16 = r*2 + fl, ks32 = (s0>>5) + kl
    int piece = tid >> 6;            // 0..3
    int fl = piece >> 1, kl = piece & 1;
    int ln = tid & 63;
    int x = fl * 16 + (ln & 15);
    int s_loc = kl * 32 + (ln >> 4) * 8;
    i32x4 va = *(const i32x4*)((const char*)ab_s[0] + (x * 72 + s_loc) * 2);
    i32x4 vb = *(const i32x4*)((const char*)ab_s[1] + (x * 72 + s_loc) * 2);
    size_t off = ((((size_t)r * 2 + fl) * 4 + (s0 >> 5) + kl) * 64 + ln) * 16;
    *(i32x4*)((char*)aTf + off) = va;
    *(i32x4*)((char*)bTf + off) = vb;
}

// ---------------- kernel 2: fused outer-product + w_out contraction ----------------
// grid (96 bj, 48 bi), 512 thr (8 waves), O-tile 256(i:8res) x 128(j:4res), LDS 64 KB.
// ph2: 16x16x32, B-frags LDS (lane-linear), A-frags coalesced L2 bursts.
// ph4: 32x32x16, waves = (z-quarter x k-half), f32 partials in [0,32K), coalesced reduce.
__global__ __launch_bounds__(512, 4) void k_opm(
    const short* __restrict__ aTf, const short* __restrict__ bTf,
    const short* __restrict__ wbTf, const float* __restrict__ b_out,
    float* __restrict__ out) {
    __shared__ __align__(16) char smem[65536];
    int tid = threadIdx.x, lane = tid & 63, w = tid >> 6;
    int g = lane >> 4, r16 = lane & 15;
    int l32 = lane & 31, h = lane >> 5;
    int wm = w & 3, wn = w >> 2;            // ph2 wave grid: 4(m-64) x 2(n-64)
    int bj = blockIdx.x, bi = blockIdx.y;

    // ---- stage B-frags (32 KB, verbatim bTf[bj] region) into smem[0,32K)
    const char* gB = (const char*)bTf + (size_t)bj * 32768;
#pragma unroll
    for (int it = 0; it < 4; ++it) {
        int q = it * 8192 + tid * 16;
        __builtin_amdgcn_global_load_lds(
            (const __attribute__((address_space(1))) void*)(gB + q),
            (__attribute__((address_space(3))) void*)(smem + q), 16, 0, 0);
    }
    __syncthreads();

    // ---- ph2: O[256x128]; acc[mi][ni]: m = wm*64+mi*16+r16, n = wn*64+ni*16+g*4+rr
    f32x4 acc[4][4] = {};
    const char* gA = (const char*)aTf + ((size_t)bi * 16 + wm * 4) * 4096;
#pragma unroll
    for (int ks = 0; ks < 4; ++ks) {
        bf16x8 bf[4], af[4];
#pragma unroll
        for (int ni = 0; ni < 4; ++ni)
            bf[ni] = *(const bf16x8*)(smem + (((wn * 4 + ni) * 4 + ks) * 64 + lane) * 16);
#pragma unroll
        for (int mi = 0; mi < 4; ++mi)
            af[mi] = *(const bf16x8*)(gA + ((mi * 4 + ks) * 64 + lane) * 16);
        __builtin_amdgcn_s_setprio(1);
#pragma unroll
        for (int mi = 0; mi < 4; ++mi)
#pragma unroll
            for (int ni = 0; ni < 4; ++ni)
                acc[mi][ni] = __builtin_amdgcn_mfma_f32_16x16x32_bf16(bf[ni], af[mi], acc[mi][ni], 0, 0, 0);
        __builtin_amdgcn_s_setprio(0);
    }
    __syncthreads();   // B reads done -> smem becomes A2

    // ---- ph3: O -> A2 bf16 [p=i*4+j][k=x*32+y], dual-XOR swizzle
#pragma unroll
    for (int mi = 0; mi < 4; ++mi)
#pragma unroll
        for (int ni = 0; ni < 4; ++ni) {
            int m = wm * 64 + mi * 16 + r16;
            int nb = wn * 64 + ni * 16 + g * 4;
            int i = m >> 5, x = m & 31;
            int j = nb >> 5, y0 = nb & 31;
            int p = i * 4 + j;
            int byte = (p * 2048 + x * 64 + y0 * 2) ^ (((p & 7) ^ (x & 7)) << 4);
            short4 pk;
            pk.x = tobf16(acc[mi][ni][0]);
            pk.y = tobf16(acc[mi][ni][1]);
            pk.z = tobf16(acc[mi][ni][2]);
            pk.w = tobf16(acc[mi][ni][3]);
            *(short4*)(smem + byte) = pk;
        }
    __syncthreads();

    // ---- ph4: 32x32x16; wave (kh = w&1, zq = w>>1): slab [32p x 32z], k-half 512
    int kh = w & 1, zq = w >> 1;
    f32x16 c2a = {0,0,0,0,0,0,0,0,0,0,0,0,0,0,0,0};
    f32x16 c2b = {0,0,0,0,0,0,0,0,0,0,0,0,0,0,0,0};
    const short* wbase = wbTf + (size_t)((zq * 64 + kh * 32) * 64) * 8;
#pragma unroll 8
    for (int ks = 0; ks < 32; ++ks) {
        int x = (kh * 32 + ks) >> 1;
        int byte = (l32 * 2048 + kh * 1024 + ks * 32 + h * 16) ^ ((((l32 & 7) ^ (x & 7))) << 4);
        bf16x8 a2f = *(const bf16x8*)(smem + byte);
        bf16x8 wbf = *(const bf16x8*)(wbase + (ks * 64 + lane) * 8);
        if (ks & 1) c2b = __builtin_amdgcn_mfma_f32_32x32x16_bf16(a2f, wbf, c2b, 0, 0, 0);
        else        c2a = __builtin_amdgcn_mfma_f32_32x32x16_bf16(a2f, wbf, c2a, 0, 0, 0);
    }
    f32x16 c2 = c2a + c2b;
    __syncthreads();   // all A2 reads done -> [0,32K) becomes Pp

    // ---- Pp write: slab (zq*2+kh) 4KB: [z' 32][p 32] f32, ^((z'&7)<<4)
#pragma unroll
    for (int q = 0; q < 4; ++q) {
        f32x4 v;
        v[0] = c2[q * 4 + 0]; v[1] = c2[q * 4 + 1];
        v[2] = c2[q * 4 + 2]; v[3] = c2[q * 4 + 3];
        int byte = ((zq * 2 + kh) * 4096 + l32 * 128 + q * 32 + h * 16) ^ ((l32 & 7) << 4);
        *(f32x4*)(smem + byte) = v;
    }
    __syncthreads();

    // ---- reduce kh-halves + coalesced store
    int z = tid & 127, zq2 = z >> 5, zp = z & 31;
    int pr0 = tid >> 7;
    float bo = b_out[z];
#pragma unroll
    for (int stp = 0; stp < 2; ++stp) {
        int prq = pr0 + stp * 4;                 // p-quad 0..7
        int base = zq2 * 8192 + zp * 128 + prq * 16;
        int sw = (zp & 7) << 4;
        f32x4 v0 = *(const f32x4*)(smem + (base ^ sw));
        f32x4 v1 = *(const f32x4*)(smem + ((base + 4096) ^ sw));
#pragma unroll
        for (int rr = 0; rr < 4; ++rr) {
            int p = prq * 4 + rr;
            int ig = bi * 8 + (p >> 2);
            int jg = bj * 4 + (p & 3);
            out[((size_t)ig * R_RES + jg) * CZ + z] = (v0[rr] + v1[rr] + bo) * (1.0f / 128.0f);
        }
    }
}

extern "C" void kernel_launch(void* const* d_in, const int* in_sizes, int n_in,
                              void* d_out, int out_size, void* d_ws, size_t ws_size,
                              hipStream_t stream) {
    const float* M     = (const float*)d_in[0];
    const float* ln_g  = (const float*)d_in[1];
    const float* ln_b  = (const float*)d_in[2];
    const float* w1    = (const float*)d_in[3];
    const float* b1    = (const float*)d_in[4];
    const float* w2    = (const float*)d_in[5];
    const float* b2    = (const float*)d_in[6];
    const float* w_out = (const float*)d_in[7];
    const float* b_out = (const float*)d_in[8];
    float* out = (float*)d_out;

    short* aTf  = (short*)d_ws;             // 12288 x 128 bf16, fragment-tiled
    short* bTf  = aTf + 12288 * 128;        // 12288 x 128 bf16, fragment-tiled
    short* wbTf = bTf + 12288 * 128;        // 128 x 1024 bf16, fragment-tiled
    short* wcT  = wbTf + 128 * 1024;        // 64 x 256 bf16

    k_transpose_wout<<<dim3(16, 2), 256, 0, stream>>>(w_out, wbTf);
    k_pack_w12<<<64, 256, 0, stream>>>(w1, w2, wcT);
    k_ln_proj<<<768, 256, 0, stream>>>(M, ln_g, ln_b, b1, b2, wcT, aTf, bTf);
    k_opm<<<dim3(96, 48), 512, 0, stream>>>(aTf, bTf, wbTf, b_out, out);
}